// Round 5
// baseline (2979.057 us; speedup 1.0000x reference)
//
#include <hip/hip_runtime.h>
#include <hip/hip_bf16.h>
#include <math.h>

// Problem constants
#define BB 128
#define TT 1024
#define DD 256
#define HH 256
#define MM (BB * TT)
#define NN3 768

#define NCONS 8          // consumer (gru) blocks
#define NPROD 240        // producer (xproj) blocks: 6 n-slices x 40 batch-groups
#define WIN_TILES 768    // tiles per 128-step window: 6 nb x 128 b
#define XW_BYTES ((size_t)MM * NN3 * sizeof(unsigned short))   // 192 MiB

typedef __attribute__((ext_vector_type(8))) short short8;
typedef __attribute__((ext_vector_type(4))) float f32x4;
typedef __attribute__((address_space(1))) unsigned int gu32;
typedef __attribute__((address_space(3))) unsigned int lu32;

static __device__ __forceinline__ float bf2f(unsigned int u16) {
    return __uint_as_float(u16 << 16);
}
// RNE
static __device__ __forceinline__ unsigned short f2bf(float f) {
    unsigned int u = __float_as_uint(f);
    unsigned int r = u + 0x7FFFu + ((u >> 16) & 1u);
    return (unsigned short)(r >> 16);
}
// round-half-up, 2 ops
static __device__ __forceinline__ unsigned short f2bf_fast(float f) {
    return (unsigned short)((__float_as_uint(f) + 0x8000u) >> 16);
}

static __device__ __forceinline__ void barrier_lgkm() {
    asm volatile("s_waitcnt lgkmcnt(0)\n\ts_barrier" ::: "memory");
}
static __device__ __forceinline__ void barrier_full() {
    asm volatile("s_waitcnt vmcnt(0) lgkmcnt(0)\n\ts_barrier" ::: "memory");
}

// ---------------------------------------------------------------------------
// Fused kernel. Blocks 0..7: persistent-register MFMA GRU recurrence (one per
// batch-group of 16). Blocks 8..247: xproj producers filling xw in
// 128-timestep windows, signalling via cnt[8] (device-scope release/acquire).
// xw layout per (t, bid): 12288 shorts; element (ti, lane, ii):
//   ti = gate*16 + (col>>4); lane = (brow>>2)*16 + (col&15); ii = brow&3.
// ---------------------------------------------------------------------------
__global__ __launch_bounds__(512)
__attribute__((amdgpu_waves_per_eu(2, 2)))
void gru_fused_kernel(
    const float* __restrict__ x,
    const float* __restrict__ Wz, const float* __restrict__ Wr,
    const float* __restrict__ Wh,
    const float* __restrict__ Uz, const float* __restrict__ Ur,
    const float* __restrict__ Uh,
    const float* __restrict__ bz, const float* __restrict__ br,
    const float* __restrict__ bh,
    unsigned short* __restrict__ xw,
    unsigned int* __restrict__ cnt,
    float* __restrict__ out)
{
    const int tid  = threadIdx.x;
    const int lane = tid & 63;
    const int wv   = tid >> 6;
    const int nq   = lane & 15;
    const int kq   = lane >> 4;

    if (blockIdx.x >= NCONS) {
        // ================= producer =================
        const int p   = blockIdx.x - NCONS;
        const int nb  = p % 6;        // n-slice (128 cols)
        const int bg  = p / 6;        // batch-group 0..39
        const int n0  = nb * 128;
        const int g   = n0 >> 8;
        const int nc0 = n0 & 255;
        const float* W    = (g == 0) ? Wz : (g == 1 ? Wr : Wh);
        const float* bias = (g == 0) ? bz : (g == 1 ? br : bh);
        const int nh = wv >> 2;       // n-half (64 cols) within slice
        const int mq = wv & 3;        // m-quarter (32 rows) within tile

        // one-time W fragment gather (RNE), register-resident for all windows
        short8 wf[8][4];
#pragma unroll
        for (int c = 0; c < 8; ++c)
#pragma unroll
            for (int nt = 0; nt < 4; ++nt) {
                short8 f;
                const int col = nc0 + nh * 64 + nt * 16 + nq;
#pragma unroll
                for (int j = 0; j < 8; ++j)
                    f[j] = (short)f2bf(W[(size_t)(c * 32 + kq * 8 + j) * HH + col]);
                wf[c][nt] = f;
            }
        float bv[4];
#pragma unroll
        for (int nt = 0; nt < 4; ++nt)
            bv[nt] = bias[nc0 + nh * 64 + nt * 16 + nq];

        for (int w = 0; w < 8; ++w) {
            for (int b = bg; b < BB; b += 40) {
                const int m0 = (b * 8 + w) * 128;
                f32x4 acc[2][4];
#pragma unroll
                for (int mi = 0; mi < 2; ++mi)
#pragma unroll
                    for (int nt = 0; nt < 4; ++nt)
                        acc[mi][nt] = (f32x4){0.f, 0.f, 0.f, 0.f};

#pragma unroll
                for (int c = 0; c < 8; ++c) {
                    short8 af[2];
#pragma unroll
                    for (int mi = 0; mi < 2; ++mi) {
                        const float* xp = &x[(size_t)(m0 + mq * 32 + mi * 16 + nq) * DD
                                             + c * 32 + kq * 8];
                        float4 f0 = *(const float4*)xp;
                        float4 f1 = *(const float4*)(xp + 4);
                        short8 a;
                        a[0] = (short)f2bf_fast(f0.x); a[1] = (short)f2bf_fast(f0.y);
                        a[2] = (short)f2bf_fast(f0.z); a[3] = (short)f2bf_fast(f0.w);
                        a[4] = (short)f2bf_fast(f1.x); a[5] = (short)f2bf_fast(f1.y);
                        a[6] = (short)f2bf_fast(f1.z); a[7] = (short)f2bf_fast(f1.w);
                        af[mi] = a;
                    }
#pragma unroll
                    for (int mi = 0; mi < 2; ++mi)
#pragma unroll
                        for (int nt = 0; nt < 4; ++nt)
                            acc[mi][nt] = __builtin_amdgcn_mfma_f32_16x16x32_bf16(
                                af[mi], wf[c][nt], acc[mi][nt], 0, 0, 0);
                }

                // epilogue: +bias, bf16, recurrence-native scatter
                const int tb   = (m0 & 1023) + mq * 32;
                const int bb   = m0 >> 10;
                const int bid2 = bb >> 4, brow = bb & 15;
                const int lane4 = (brow >> 2) * 16 + nq;
                const int ii    = brow & 3;
#pragma unroll
                for (int mi = 0; mi < 2; ++mi)
#pragma unroll
                    for (int nt = 0; nt < 4; ++nt) {
                        int ti = g * 16 + (nc0 >> 4) + nh * 4 + nt;
#pragma unroll
                        for (int i = 0; i < 4; ++i) {
                            int t = tb + mi * 16 + kq * 4 + i;
                            xw[(size_t)(t * 8 + bid2) * 12288
                               + (size_t)(ti * 256 + lane4 * 4 + ii)] =
                                f2bf(acc[mi][nt][i] + bv[nt]);
                        }
                    }

                __syncthreads();   // all tile stores issued & drained (vmcnt0)
                if (tid == 0) {
                    __threadfence();   // agent-scope: writeback L2 before flag
                    __hip_atomic_fetch_add(&cnt[w], 1u, __ATOMIC_RELEASE,
                                           __HIP_MEMORY_SCOPE_AGENT);
                }
            }
        }
        return;
    }

    // ================= consumer: GRU recurrence =================
    __shared__ unsigned short xstage[2][12288];
    __shared__ short hA[16][264];
    __shared__ short rhA[16][264];

    const int bid = blockIdx.x;

    // persistent weight fragments (192 regs/lane, live in AGPR+VGPR)
    short8 wzr[4][8];
#pragma unroll
    for (int q = 0; q < 4; ++q) {
        const float* U = (q < 2) ? Uz : Ur;
        const int col0 = (wv + 8 * (q & 1)) * 16;
#pragma unroll
        for (int c = 0; c < 8; ++c) {
            short8 f;
#pragma unroll
            for (int j = 0; j < 8; ++j)
                f[j] = (short)f2bf(U[(size_t)(c * 32 + kq * 8 + j) * HH + col0 + nq]);
            wzr[q][c] = f;
        }
    }
    short8 wh[2][8];
#pragma unroll
    for (int tj = 0; tj < 2; ++tj) {
        const int col0 = (wv + 8 * tj) * 16;
#pragma unroll
        for (int c = 0; c < 8; ++c) {
            short8 f;
#pragma unroll
            for (int j = 0; j < 8; ++j)
                f[j] = (short)f2bf(Uh[(size_t)(c * 32 + kq * 8 + j) * HH + col0 + nq]);
            wh[tj][c] = f;
        }
    }

    for (int idx = tid; idx < 16 * 264; idx += 512) ((short*)hA)[idx] = 0;
    float hprev[8];
#pragma unroll
    for (int i = 0; i < 8; ++i) hprev[i] = 0.f;

    auto stage = [&](int t, int buf) {
        const char* gsrc = (const char*)(xw + (size_t)(t * 8 + bid) * 12288);
        char* lbase = (char*)&xstage[buf][0];
        int woff = wv * 3072;
#pragma unroll
        for (int ld = 0; ld < 3; ++ld) {
            int off = woff + ld * 1024;
            __builtin_amdgcn_global_load_lds(
                (const gu32*)(gsrc + off + lane * 16),
                (lu32*)(lbase + off), 16, 0, 0);
        }
    };

    auto wait_window = [&](int w2) {
        if (tid == 0) {
            while (__hip_atomic_load(&cnt[w2], __ATOMIC_RELAXED,
                                     __HIP_MEMORY_SCOPE_AGENT) < WIN_TILES) {}
            __threadfence();   // acquire side: invalidate stale caches
        }
        __syncthreads();
    };

    int done_w = 0;
    wait_window(0);
    stage(0, 0);
    barrier_full();

    const int tiz = wv;
    auto step = [&](int t, int par) {
        int tneed = (t + 1 < TT) ? (t + 1) : (TT - 1);
        int wneed = tneed >> 7;
        if (wneed > done_w) { wait_window(wneed); done_w = wneed; }
        stage(tneed, par ^ 1);

        const unsigned short* xs = &xstage[par][0];

        // ---- phase A: accA init = x (z,r), MFMA chains over h ----
        f32x4 accA[4];
#pragma unroll
        for (int q = 0; q < 4; ++q) {
            int ti = (q < 2 ? 0 : 16) + tiz + 8 * (q & 1);
            uint2 u = *(const uint2*)&xs[(ti * 64 + lane) * 4];
            accA[q][0] = bf2f(u.x & 0xffffu);
            accA[q][1] = bf2f(u.x >> 16);
            accA[q][2] = bf2f(u.y & 0xffffu);
            accA[q][3] = bf2f(u.y >> 16);
        }
#pragma unroll
        for (int c = 0; c < 8; ++c) {
            short8 af = *(const short8*)&hA[nq][c * 32 + kq * 8];
#pragma unroll
            for (int q = 0; q < 4; ++q)
                accA[q] = __builtin_amdgcn_mfma_f32_16x16x32_bf16(
                    af, wzr[q][c], accA[q], 0, 0, 0);
        }

        // r epilogue (z deferred to phase B)
#pragma unroll
        for (int tj = 0; tj < 2; ++tj) {
            int col = (tiz + 8 * tj) * 16 + nq;
#pragma unroll
            for (int i = 0; i < 4; ++i) {
                float r = __builtin_amdgcn_fmed3f(
                    __builtin_fmaf(0.2f, accA[2 + tj][i], 0.5f), 0.f, 1.f);
                rhA[kq * 4 + i][col] = (short)f2bf_fast(r * hprev[tj * 4 + i]);
            }
        }
        barrier_lgkm();

        // ---- phase B: accH init = xh, MFMA over r*h, z + h epilogue ----
        f32x4 accH[2];
#pragma unroll
        for (int tj = 0; tj < 2; ++tj) {
            int ti = 32 + tiz + 8 * tj;
            uint2 u = *(const uint2*)&xs[(ti * 64 + lane) * 4];
            accH[tj][0] = bf2f(u.x & 0xffffu);
            accH[tj][1] = bf2f(u.x >> 16);
            accH[tj][2] = bf2f(u.y & 0xffffu);
            accH[tj][3] = bf2f(u.y >> 16);
        }
#pragma unroll
        for (int c = 0; c < 8; ++c) {
            short8 af = *(const short8*)&rhA[nq][c * 32 + kq * 8];
            accH[0] = __builtin_amdgcn_mfma_f32_16x16x32_bf16(af, wh[0][c], accH[0], 0, 0, 0);
            accH[1] = __builtin_amdgcn_mfma_f32_16x16x32_bf16(af, wh[1][c], accH[1], 0, 0, 0);
        }

#pragma unroll
        for (int tj = 0; tj < 2; ++tj) {
            int col = (tiz + 8 * tj) * 16 + nq;
#pragma unroll
            for (int i = 0; i < 4; ++i) {
                int idx = tj * 4 + i;
                float z = __builtin_amdgcn_fmed3f(
                    __builtin_fmaf(0.2f, accA[tj][i], 0.5f), 0.f, 1.f);
                float a = __builtin_amdgcn_fmed3f(accH[tj][i], -12.f, 12.f);
                float a2 = a * 2.88539008f;
                float e;
                asm("v_exp_f32 %0, %1" : "=v"(e) : "v"(a2));   // e^(2a)
                float hh = __builtin_fmaf(-2.f, __builtin_amdgcn_rcpf(e + 1.f), 1.f);
                float hn = __builtin_fmaf(z, hprev[idx] - hh, hh);
                hprev[idx] = hn;
                hA[kq * 4 + i][col] = (short)f2bf_fast(hn);
            }
        }
        barrier_full();
    };

    for (int t = 0; t < TT; t += 2) {
        step(t, 0);
        step(t + 1, 1);
    }

#pragma unroll
    for (int tj = 0; tj < 2; ++tj) {
        int col = (tiz + 8 * tj) * 16 + nq;
#pragma unroll
        for (int i = 0; i < 4; ++i)
            out[(size_t)(bid * 16 + kq * 4 + i) * HH + col] = hprev[tj * 4 + i];
    }
}

// ---------------------------------------------------------------------------
extern "C" void kernel_launch(void* const* d_in, const int* in_sizes, int n_in,
                              void* d_out, int out_size, void* d_ws, size_t ws_size,
                              hipStream_t stream) {
    const float* x  = (const float*)d_in[0];
    const float* Wz = (const float*)d_in[1];
    const float* Wr = (const float*)d_in[2];
    const float* Wh = (const float*)d_in[3];
    const float* Uz = (const float*)d_in[4];
    const float* Ur = (const float*)d_in[5];
    const float* Uh = (const float*)d_in[6];
    const float* bz = (const float*)d_in[7];
    const float* br = (const float*)d_in[8];
    const float* bh = (const float*)d_in[9];
    float* out = (float*)d_out;

    // workspace: [xw: 192 MiB][cnt: 8 uints]
    unsigned short* xw = (unsigned short*)d_ws;
    unsigned int* cnt = (unsigned int*)((char*)d_ws + XW_BYTES);

    hipMemsetAsync(cnt, 0, 8 * sizeof(unsigned int), stream);

    gru_fused_kernel<<<NCONS + NPROD, 512, 0, stream>>>(
        x, Wz, Wr, Wh, Uz, Ur, Uh, bz, br, bh, xw, cnt, out);
}